// Round 9
// baseline (751.483 us; speedup 1.0000x reference)
//
#include <hip/hip_runtime.h>

#define NAT 20000
#define NE  640000
#define NT  2000000
#define CH  128
#define EF  64
#define NB  4096
#define PI_F 3.14159265358979f
#define NLOG2E (-1.44269504088896f)

typedef __attribute__((ext_vector_type(8))) __bf16 bf16x8;
typedef __attribute__((ext_vector_type(4))) float floatx4;
typedef __attribute__((ext_vector_type(2))) float floatx2;

__device__ __forceinline__ float fsigmoid(float x) {
    return __builtin_amdgcn_rcpf(1.0f + __expf(-x));
}
__device__ __forceinline__ float fsilu(float x) { return x * fsigmoid(x); }

// packed-f32 helpers: scalar v_exp/v_rcp (no packed trans), packed mul/add around
__device__ __forceinline__ floatx2 fsigmoid2(floatx2 x) {
    floatx2 nx = x * NLOG2E;
    floatx2 e = {__builtin_amdgcn_exp2f(nx.x), __builtin_amdgcn_exp2f(nx.y)};
    floatx2 d = e + 1.0f;
    return floatx2{__builtin_amdgcn_rcpf(d.x), __builtin_amdgcn_rcpf(d.y)};
}
__device__ __forceinline__ floatx2 fsilu2(floatx2 x) { return x * fsigmoid2(x); }

// ---------------- K1/K6: Y[M x 128] = X[M x 128] @ W[128 x 128] ----------------
// In-place safe (Y==X): block loads its own 32 X-rows into LDS before storing.
__global__ __launch_bounds__(256) void gemm128(const float* __restrict__ X,
                                               const float* __restrict__ W,
                                               float* __restrict__ Y) {
    __shared__ float Xs[32 * 128];
    __shared__ float Ws[32 * 128];
    int tid = threadIdx.x;
    int row0 = blockIdx.x * 32;

    const float4* Xg = (const float4*)(X + (size_t)row0 * 128);
    float4* Xs4 = (float4*)Xs;
#pragma unroll
    for (int i = 0; i < 4; ++i) Xs4[tid + 256 * i] = Xg[tid + 256 * i];

    int c = tid & 127, half = tid >> 7;
    float acc[16];
#pragma unroll
    for (int r = 0; r < 16; ++r) acc[r] = 0.0f;

    for (int kb = 0; kb < 4; ++kb) {
        __syncthreads();
        const float4* Wg = (const float4*)(W + kb * 32 * 128);
        float4* Ws4 = (float4*)Ws;
#pragma unroll
        for (int i = 0; i < 4; ++i) Ws4[tid + 256 * i] = Wg[tid + 256 * i];
        __syncthreads();
#pragma unroll
        for (int kk = 0; kk < 32; ++kk) {
            float wv = Ws[kk * 128 + c];
            int k = kb * 32 + kk;
#pragma unroll
            for (int r = 0; r < 16; ++r)
                acc[r] += Xs[(half * 16 + r) * 128 + k] * wv;
        }
    }
#pragma unroll
    for (int r = 0; r < 16; ++r)
        Y[(size_t)(row0 + half * 16 + r) * 128 + c] = acc[r];
}

// ---------------- K2: build two-body LUT ----------------
__global__ __launch_bounds__(128) void build_lut(const float* __restrict__ W1,
                                                 const float* __restrict__ W2,
                                                 const float* __restrict__ G1,
                                                 const float* __restrict__ G2,
                                                 float* __restrict__ lut) {
    __shared__ float rb[64], hm[64], hg[64];
    int p = blockIdx.x, t = threadIdx.x;
    float d = p * (5.0f / NB);
    if (t < 64) {
        float ctr = t * (5.0f / 63.0f);
        float sig = 5.0f / 64.0f;
        float z = (d - ctr);
        float g = __expf(-z * z / (2.0f * sig * sig));
        float env = (d < 5.0f) ? 0.5f * (1.0f + __cosf(PI_F * d / 5.0f)) : 0.0f;
        rb[t] = g * env;
    }
    __syncthreads();
    {
        int j = t & 63;
        const float* Wm = (t < 64) ? W1 : G1;
        float s = 0.0f;
        for (int k = 0; k < 64; ++k) s += rb[k] * Wm[k * 64 + j];
        float hv = fsilu(s);
        if (t < 64) hm[j] = hv; else hg[j] = hv;
    }
    __syncthreads();
    {
        float m = 0.0f, g = 0.0f;
        for (int j = 0; j < 64; ++j) {
            m += hm[j] * W2[j * 128 + t];
            g += hg[j] * G2[j * 128 + t];
        }
        lut[(size_t)p * 128 + t] = m * fsigmoid(g);
    }
}

// ---------------- sort passes ----------------
__global__ __launch_bounds__(256) void hist_k(const int* __restrict__ tri,
                                              const int* __restrict__ nl,
                                              int* __restrict__ tcnt,
                                              int* __restrict__ ecnt) {
    int stride = gridDim.x * 256;
    for (int g = blockIdx.x * 256 + threadIdx.x; g < NT + NE; g += stride) {
        if (g < NT) atomicAdd(&tcnt[tri[(size_t)g * 3 + 1]], 1);
        else        atomicAdd(&ecnt[nl[g - NT]], 1);
    }
}

__global__ __launch_bounds__(1024) void scan20k(int* __restrict__ tcnt, int* __restrict__ toff, int* __restrict__ tcur,
                                                int* __restrict__ ecnt, int* __restrict__ eoff, int* __restrict__ ecur) {
    int* cnt; int* off; int* cur;
    if (blockIdx.x == 0) { cnt = tcnt; off = toff; cur = tcur; }
    else                 { cnt = ecnt; off = eoff; cur = ecur; }
    __shared__ int part[1024];
    int t = threadIdx.x;
    const int PER = 20;
    int vals[PER]; int lsum = 0;
#pragma unroll
    for (int i = 0; i < PER; ++i) {
        int idx = t * PER + i;
        int v = (idx < NAT) ? cnt[idx] : 0;
        vals[i] = v; lsum += v;
    }
    part[t] = lsum;
    __syncthreads();
    for (int d = 1; d < 1024; d <<= 1) {
        int add = (t >= d) ? part[t - d] : 0;
        __syncthreads();
        part[t] += add;
        __syncthreads();
    }
    int run = part[t] - lsum;
#pragma unroll
    for (int i = 0; i < PER; ++i) {
        int idx = t * PER + i;
        if (idx < NAT) { off[idx] = run; cur[idx] = run; run += vals[i]; }
    }
    if (t == 1023) off[NAT] = part[1023];
}

// scatter payloads: tdata 12B (rij, rik, cos); edata 12B (dist, a1, edge-id)
__global__ __launch_bounds__(256) void scatter_k(const int* __restrict__ tri,
                                                 const int* __restrict__ nl,
                                                 const float* __restrict__ rij,
                                                 const float* __restrict__ rik,
                                                 const float* __restrict__ ang,
                                                 const float* __restrict__ dist,
                                                 int* __restrict__ tcur, int* __restrict__ ecur,
                                                 float* __restrict__ tdata,
                                                 float* __restrict__ edata) {
    int stride = gridDim.x * 256;
    for (int g = blockIdx.x * 256 + threadIdx.x; g < NT + NE; g += stride) {
        if (g < NT) {
            int p = atomicAdd(&tcur[tri[(size_t)g * 3 + 1]], 1);
            float* dst = tdata + (size_t)p * 3;
            dst[0] = rij[g];
            dst[1] = rik[g];
            dst[2] = __cosf(ang[g]);
        } else {
            int e = g - NT;
            int p = atomicAdd(&ecur[nl[e]], 1);
            float* dst = edata + (size_t)p * 3;
            dst[0] = dist[e];
            ((int*)dst)[1] = nl[NE + e];
            ((int*)dst)[2] = e;
        }
    }
}

// ---------------- K3: two-body + fused three-body inject (runs AFTER threebody) ----------
__global__ __launch_bounds__(256) void twobody_sorted(const float* __restrict__ edata,
                                                      const float* __restrict__ h,
                                                      const float* __restrict__ lut,
                                                      const int* __restrict__ eoff,
                                                      const float* __restrict__ W3,
                                                      float* __restrict__ acc) {
    int tid = threadIdx.x, lane = tid & 63;
    int wid = blockIdx.x * 4 + (tid >> 6);
    int nw = gridDim.x * 4;
    int c = lane << 1;
    for (int a = wid; a < NAT; a += nw) {
        int base = eoff[a];
        int cnt = eoff[a + 1] - base;
        float s0 = 0.f, s1 = 0.f, t0 = 0.f, t1 = 0.f;
        for (int i0 = 0; i0 < cnt; i0 += 64) {
            int rem = cnt - i0; if (rem > 64) rem = 64;
            float ed = 0.f; int ea1 = 0, eid = 0x7fffffff;
            if (lane < rem) {
                const float* p = edata + (size_t)(base + i0 + lane) * 3;
                ed = p[0];
                ea1 = ((const int*)p)[1];
                eid = ((const int*)p)[2];
            }
            int j = 0;
            for (; j + 2 <= rem; j += 2) {
                float dA = __shfl(ed, j);
                int aA = __shfl(ea1, j);
                int eA = __shfl(eid, j);
                float dB = __shfl(ed, j + 1);
                int aB = __shfl(ea1, j + 1);
                int eB = __shfl(eid, j + 1);
                float xA = dA * ((float)NB / 5.0f);
                int iA = (int)xA; if (iA > NB - 1) iA = NB - 1;
                float fA = xA - (float)iA;
                float xB = dB * ((float)NB / 5.0f);
                int iB = (int)xB; if (iB > NB - 1) iB = NB - 1;
                float fB = xB - (float)iB;
                float2 l0A = *(const float2*)&lut[(size_t)iA * 128 + c];
                float2 l1A = *(const float2*)&lut[(size_t)(iA + 1) * 128 + c];
                float2 hvA = *(const float2*)&h[(size_t)aA * 128 + c];
                float2 l0B = *(const float2*)&lut[(size_t)iB * 128 + c];
                float2 l1B = *(const float2*)&lut[(size_t)(iB + 1) * 128 + c];
                float2 hvB = *(const float2*)&h[(size_t)aB * 128 + c];
                s0 += hvA.x * (l0A.x + (l1A.x - l0A.x) * fA);
                s1 += hvA.y * (l0A.y + (l1A.y - l0A.y) * fA);
                t0 += hvB.x * (l0B.x + (l1B.x - l0B.x) * fB);
                t1 += hvB.y * (l0B.y + (l1B.y - l0B.y) * fB);
                if (eA < NAT) {   // wave-uniform after shuffle: three-body inject
                    float2 hv3 = *(const float2*)&h[(size_t)eA * 128 + c];
                    float2 w3 = *(const float2*)&W3[(size_t)eA * 128 + c];
                    s0 += hv3.x * w3.x; s1 += hv3.y * w3.y;
                }
                if (eB < NAT) {
                    float2 hv3 = *(const float2*)&h[(size_t)eB * 128 + c];
                    float2 w3 = *(const float2*)&W3[(size_t)eB * 128 + c];
                    t0 += hv3.x * w3.x; t1 += hv3.y * w3.y;
                }
            }
            if (j < rem) {
                float d = __shfl(ed, j);
                int a1 = __shfl(ea1, j);
                int e = __shfl(eid, j);
                float x = d * ((float)NB / 5.0f);
                int i = (int)x; if (i > NB - 1) i = NB - 1;
                float f = x - (float)i;
                float2 l0 = *(const float2*)&lut[(size_t)i * 128 + c];
                float2 l1 = *(const float2*)&lut[(size_t)(i + 1) * 128 + c];
                float2 hv = *(const float2*)&h[(size_t)a1 * 128 + c];
                s0 += hv.x * (l0.x + (l1.x - l0.x) * f);
                s1 += hv.y * (l0.y + (l1.y - l0.y) * f);
                if (e < NAT) {
                    float2 hv3 = *(const float2*)&h[(size_t)e * 128 + c];
                    float2 w3 = *(const float2*)&W3[(size_t)e * 128 + c];
                    s0 += hv3.x * w3.x; s1 += hv3.y * w3.y;
                }
            }
        }
        acc[(size_t)a * 128 + c] = s0 + t0;
        acc[(size_t)a * 128 + c + 1] = s1 + t1;
    }
}

// ---------------- K4: three-body, sorted payloads, register accumulation ----------------
// R6: sched_barrier fences hoisting (VGPR 172->64). R8 showed the residual 38% stall is
// LDS-pipe contention: 32 ds_read_b128 per 16-triplet batch re-reading invariant B.
// R9: build all 4 A-fragment pairs per 64-triplet chunk, then tile-outer/ms-inner --
// each tile's 4 B-reads now feed 16 MFMAs (4x less LDS traffic). sched_barrier at
// tile-loop top caps the B prefetch window at one tile.
__global__ __launch_bounds__(256) void threebody_sorted(const float* __restrict__ tdata,
                                                        const int* __restrict__ toff,
                                                        const float* __restrict__ thW1,
                                                        const float* __restrict__ thW2,
                                                        const float* __restrict__ thG1,
                                                        const float* __restrict__ thG2,
                                                        float* __restrict__ W3) {
    __shared__ __bf16 lw2[64 * 128];
    __shared__ __bf16 lg2[64 * 128];
    __shared__ float lw1[192];
    __shared__ float lg1[192];
    int tid = threadIdx.x;
    for (int i = tid; i < 192; i += 256) { lw1[i] = thW1[i]; lg1[i] = thG1[i]; }
    // B-fragment swizzle (validated R1/R2): (k,c) -> (((tile*2+s)*64)+q*16+n)*8+j
    for (int e = tid; e < 64 * 128; e += 256) {
        int k = e >> 7, c = e & 127;
        int tile = c >> 4, n = c & 15, s = k >> 5, q = (k >> 3) & 3, j = k & 7;
        int li = ((((tile << 1) + s) * 64) + (q << 4) + n) * 8 + j;
        lw2[li] = (__bf16)thW2[e];
        lg2[li] = (__bf16)thG2[e];
    }
    __syncthreads();

    int lane = tid & 63;
    int q = lane >> 4, n = lane & 15;
    int lfrag = ((q << 4) + n) << 3;
    int wid = (blockIdx.x << 2) + (tid >> 6);
    int nw = gridDim.x << 2;

    for (int a = wid; a < NAT; a += nw) {
        int base = toff[a];
        int cnt = toff[a + 1] - base;
        floatx2 accT[8];
#pragma unroll
        for (int t = 0; t < 8; ++t) accT[t] = floatx2{0.f, 0.f};

        for (int i0 = 0; i0 < cnt; i0 += 64) {
            int rem = cnt - i0;
            float tx = 0.f, ty = 0.f, tz = 0.f;
            if (lane < rem) {
                const float* p = tdata + (size_t)(base + i0 + lane) * 3;
                tx = p[0]; ty = p[1]; tz = p[2];
            }
            float rrv[4], kkv[4], ccv[4];
#pragma unroll
            for (int ms = 0; ms < 4; ++ms) {
                rrv[ms] = __shfl(tx, (ms << 4) + n);
                kkv[ms] = __shfl(ty, (ms << 4) + n);
                ccv[ms] = __shfl(tz, (ms << 4) + n);
            }
            int nms = rem >= 64 ? 4 : ((rem + 15) >> 4);

            // build all A-fragment pairs for this chunk
            bf16x8 fam[4][2], fag[4][2];
#pragma unroll
            for (int ms = 0; ms < 4; ++ms) {
                if (ms >= nms) break;   // wave-uniform
                floatx2 rr2 = {rrv[ms], rrv[ms]};
                floatx2 kk2 = {kkv[ms], kkv[ms]};
                floatx2 cc2 = {ccv[ms], ccv[ms]};
#pragma unroll
                for (int s = 0; s < 2; ++s) {
                    int kb = s * 32 + (q << 3);
#pragma unroll
                    for (int j2 = 0; j2 < 4; ++j2) {
                        floatx2 um = rr2 * (*(const floatx2*)&lw1[kb + 2 * j2])
                                   + kk2 * (*(const floatx2*)&lw1[64 + kb + 2 * j2])
                                   + cc2 * (*(const floatx2*)&lw1[128 + kb + 2 * j2]);
                        floatx2 ug = rr2 * (*(const floatx2*)&lg1[kb + 2 * j2])
                                   + kk2 * (*(const floatx2*)&lg1[64 + kb + 2 * j2])
                                   + cc2 * (*(const floatx2*)&lg1[128 + kb + 2 * j2]);
                        floatx2 sm = fsilu2(um);
                        floatx2 sg = fsilu2(ug);
                        fam[ms][s][2 * j2]     = (__bf16)sm.x;
                        fam[ms][s][2 * j2 + 1] = (__bf16)sm.y;
                        fag[ms][s][2 * j2]     = (__bf16)sg.x;
                        fag[ms][s][2 * j2 + 1] = (__bf16)sg.y;
                    }
                }
            }

            // tile-outer: one B-fragment read serves all ms batches
#pragma unroll
            for (int tile = 0; tile < 8; ++tile) {
                __builtin_amdgcn_sched_barrier(0);  // cap B prefetch at one tile
                const __bf16* pw = lw2 + lfrag + tile * 1024;
                const __bf16* pg = lg2 + lfrag + tile * 1024;
                bf16x8 bw0 = *(const bf16x8*)(pw);
                bf16x8 bw1 = *(const bf16x8*)(pw + 512);
                bf16x8 bg0 = *(const bf16x8*)(pg);
                bf16x8 bg1 = *(const bf16x8*)(pg + 512);
#pragma unroll
                for (int ms = 0; ms < 4; ++ms) {
                    if (ms >= nms) break;   // wave-uniform
                    floatx4 am = {0.f, 0.f, 0.f, 0.f};
                    floatx4 ag = {0.f, 0.f, 0.f, 0.f};
                    am = __builtin_amdgcn_mfma_f32_16x16x32_bf16(fam[ms][0], bw0, am, 0, 0, 0);
                    am = __builtin_amdgcn_mfma_f32_16x16x32_bf16(fam[ms][1], bw1, am, 0, 0, 0);
                    ag = __builtin_amdgcn_mfma_f32_16x16x32_bf16(fag[ms][0], bg0, ag, 0, 0, 0);
                    ag = __builtin_amdgcn_mfma_f32_16x16x32_bf16(fag[ms][1], bg1, ag, 0, 0, 0);
                    floatx2 s01 = fsigmoid2(floatx2{ag[0], ag[1]});
                    floatx2 s23 = fsigmoid2(floatx2{ag[2], ag[3]});
                    accT[tile] += floatx2{am[0], am[1]} * s01
                                + floatx2{am[2], am[3]} * s23;
                }
            }
        }
#pragma unroll
        for (int tile = 0; tile < 8; ++tile) {
            float v = accT[tile].x + accT[tile].y;
            v += __shfl_xor(v, 16);
            v += __shfl_xor(v, 32);
            if (q == 0) W3[(size_t)a * 128 + (tile << 4) + n] = v;
        }
    }
}

extern "C" void kernel_launch(void* const* d_in, const int* in_sizes, int n_in,
                              void* d_out, int out_size, void* d_ws, size_t ws_size,
                              hipStream_t stream) {
    const float* features = (const float*)d_in[0];
    const float* dist = (const float*)d_in[1];
    const float* ang = (const float*)d_in[2];
    const float* rij = (const float*)d_in[3];
    const float* rik = (const float*)d_in[4];
    const int* nl = (const int*)d_in[5];
    const int* tri = (const int*)d_in[6];
    const float* W_pre = (const float*)d_in[7];
    const float* tbW1 = (const float*)d_in[8];
    const float* tbW2 = (const float*)d_in[9];
    const float* tbG1 = (const float*)d_in[10];
    const float* tbG2 = (const float*)d_in[11];
    const float* thW1 = (const float*)d_in[12];
    const float* thW2 = (const float*)d_in[13];
    const float* thG1 = (const float*)d_in[14];
    const float* thG2 = (const float*)d_in[15];
    const float* W_post = (const float*)d_in[16];
    float* out = (float*)d_out;

    // workspace layout (~54 MB); acc aliases d_out
    float* tdata = (float*)d_ws;                         // NT * 12B = 24 MB
    float* edata = tdata + (size_t)NT * 3;               // NE * 12B = 7.7 MB
    float* h   = edata + (size_t)NE * 3;                 // 10.24 MB
    float* W3  = h + (size_t)NAT * CH;                   // 10.24 MB
    float* lut = W3 + (size_t)NAT * CH;                  // 2.1 MB
    int* tcnt = (int*)(lut + (size_t)(NB + 1) * CH);
    int* ecnt = tcnt + NAT;
    int* toff = ecnt + NAT;                              // NAT+1
    int* eoff = toff + NAT + 1;                          // NAT+1
    int* tcur = eoff + NAT + 1;
    int* ecur = tcur + NAT;
    float* acc = out;

    hipMemsetAsync(tcnt, 0, (size_t)2 * NAT * sizeof(int), stream);

    gemm128<<<NAT / 32, 256, 0, stream>>>(features, W_pre, h);
    build_lut<<<NB + 1, 128, 0, stream>>>(tbW1, tbW2, tbG1, tbG2, lut);
    hist_k<<<1024, 256, 0, stream>>>(tri, nl, tcnt, ecnt);
    scan20k<<<2, 1024, 0, stream>>>(tcnt, toff, tcur, ecnt, eoff, ecur);
    scatter_k<<<1024, 256, 0, stream>>>(tri, nl, rij, rik, ang, dist,
                                        tcur, ecur, tdata, edata);
    // threebody BEFORE twobody: twobody consumes W3 (fused inject)
    threebody_sorted<<<1024, 256, 0, stream>>>(tdata, toff, thW1, thW2, thG1, thG2, W3);
    twobody_sorted<<<1280, 256, 0, stream>>>(edata, h, lut, eoff, W3, acc);
    gemm128<<<NAT / 32, 256, 0, stream>>>(acc, W_post, out);
}

// Round 10
// 701.816 us; speedup vs baseline: 1.0708x; 1.0708x over previous
//
#include <hip/hip_runtime.h>

#define NAT 20000
#define NE  640000
#define NT  2000000
#define CH  128
#define EF  64
#define NB  4096
#define PI_F 3.14159265358979f
#define NLOG2E (-1.44269504088896f)

typedef __attribute__((ext_vector_type(8))) __bf16 bf16x8;
typedef __attribute__((ext_vector_type(4))) float floatx4;
typedef __attribute__((ext_vector_type(2))) float floatx2;

__device__ __forceinline__ float fsigmoid(float x) {
    return __builtin_amdgcn_rcpf(1.0f + __expf(-x));
}
__device__ __forceinline__ float fsilu(float x) { return x * fsigmoid(x); }

__device__ __forceinline__ floatx2 fsigmoid2(floatx2 x) {
    floatx2 nx = x * NLOG2E;
    floatx2 e = {__builtin_amdgcn_exp2f(nx.x), __builtin_amdgcn_exp2f(nx.y)};
    floatx2 d = e + 1.0f;
    return floatx2{__builtin_amdgcn_rcpf(d.x), __builtin_amdgcn_rcpf(d.y)};
}
__device__ __forceinline__ floatx2 fsilu2(floatx2 x) { return x * fsigmoid2(x); }

// ---------------- K1/K6: Y[M x 128] = X[M x 128] @ W[128 x 128] ----------------
// R10: 4x4 register tile per thread -- 5 LDS ops per 16 FMAs (was 17 per 16).
// In-place safe (Y==X): block fully stages its own 32 X-rows before any store.
__global__ __launch_bounds__(256) void gemm128(const float* __restrict__ X,
                                               const float* __restrict__ W,
                                               float* __restrict__ Y) {
    __shared__ float Xs[32 * 128];
    __shared__ float Ws[32 * 128];
    int tid = threadIdx.x;
    int row0 = blockIdx.x * 32;

    const float4* Xg = (const float4*)(X + (size_t)row0 * 128);
    float4* Xs4 = (float4*)Xs;
#pragma unroll
    for (int i = 0; i < 4; ++i) Xs4[tid + 256 * i] = Xg[tid + 256 * i];

    int r0 = (tid >> 5) << 2;    // row group (8 groups of 4)
    int c0 = (tid & 31) << 2;    // col group (32 groups of 4)
    floatx4 acc[4];
#pragma unroll
    for (int i = 0; i < 4; ++i) acc[i] = floatx4{0.f, 0.f, 0.f, 0.f};

    for (int kb = 0; kb < 4; ++kb) {
        __syncthreads();
        const float4* Wg = (const float4*)(W + kb * 32 * 128);
        float4* Ws4 = (float4*)Ws;
#pragma unroll
        for (int i = 0; i < 4; ++i) Ws4[tid + 256 * i] = Wg[tid + 256 * i];
        __syncthreads();
#pragma unroll
        for (int kk = 0; kk < 32; ++kk) {
            int k = kb * 32 + kk;
            floatx4 wv = *(const floatx4*)&Ws[kk * 128 + c0];
            float x0 = Xs[(r0 + 0) * 128 + k];
            float x1 = Xs[(r0 + 1) * 128 + k];
            float x2 = Xs[(r0 + 2) * 128 + k];
            float x3 = Xs[(r0 + 3) * 128 + k];
            acc[0] += x0 * wv;
            acc[1] += x1 * wv;
            acc[2] += x2 * wv;
            acc[3] += x3 * wv;
        }
    }
#pragma unroll
    for (int i = 0; i < 4; ++i)
        *(floatx4*)&Y[(size_t)(row0 + r0 + i) * 128 + c0] = acc[i];
}

// ---------------- K2: build two-body LUT ----------------
__global__ __launch_bounds__(128) void build_lut(const float* __restrict__ W1,
                                                 const float* __restrict__ W2,
                                                 const float* __restrict__ G1,
                                                 const float* __restrict__ G2,
                                                 float* __restrict__ lut) {
    __shared__ float rb[64], hm[64], hg[64];
    int p = blockIdx.x, t = threadIdx.x;
    float d = p * (5.0f / NB);
    if (t < 64) {
        float ctr = t * (5.0f / 63.0f);
        float sig = 5.0f / 64.0f;
        float z = (d - ctr);
        float g = __expf(-z * z / (2.0f * sig * sig));
        float env = (d < 5.0f) ? 0.5f * (1.0f + __cosf(PI_F * d / 5.0f)) : 0.0f;
        rb[t] = g * env;
    }
    __syncthreads();
    {
        int j = t & 63;
        const float* Wm = (t < 64) ? W1 : G1;
        float s = 0.0f;
        for (int k = 0; k < 64; ++k) s += rb[k] * Wm[k * 64 + j];
        float hv = fsilu(s);
        if (t < 64) hm[j] = hv; else hg[j] = hv;
    }
    __syncthreads();
    {
        float m = 0.0f, g = 0.0f;
        for (int j = 0; j < 64; ++j) {
            m += hm[j] * W2[j * 128 + t];
            g += hg[j] * G2[j * 128 + t];
        }
        lut[(size_t)p * 128 + t] = m * fsigmoid(g);
    }
}

// ---------------- sort passes ----------------
__global__ __launch_bounds__(256) void hist_k(const int* __restrict__ tri,
                                              const int* __restrict__ nl,
                                              int* __restrict__ tcnt,
                                              int* __restrict__ ecnt) {
    int stride = gridDim.x * 256;
    for (int g = blockIdx.x * 256 + threadIdx.x; g < NT + NE; g += stride) {
        if (g < NT) atomicAdd(&tcnt[tri[(size_t)g * 3 + 1]], 1);
        else        atomicAdd(&ecnt[nl[g - NT]], 1);
    }
}

__global__ __launch_bounds__(1024) void scan20k(int* __restrict__ tcnt, int* __restrict__ toff, int* __restrict__ tcur,
                                                int* __restrict__ ecnt, int* __restrict__ eoff, int* __restrict__ ecur) {
    int* cnt; int* off; int* cur;
    if (blockIdx.x == 0) { cnt = tcnt; off = toff; cur = tcur; }
    else                 { cnt = ecnt; off = eoff; cur = ecur; }
    __shared__ int part[1024];
    int t = threadIdx.x;
    const int PER = 20;
    int vals[PER]; int lsum = 0;
#pragma unroll
    for (int i = 0; i < PER; ++i) {
        int idx = t * PER + i;
        int v = (idx < NAT) ? cnt[idx] : 0;
        vals[i] = v; lsum += v;
    }
    part[t] = lsum;
    __syncthreads();
    for (int d = 1; d < 1024; d <<= 1) {
        int add = (t >= d) ? part[t - d] : 0;
        __syncthreads();
        part[t] += add;
        __syncthreads();
    }
    int run = part[t] - lsum;
#pragma unroll
    for (int i = 0; i < PER; ++i) {
        int idx = t * PER + i;
        if (idx < NAT) { off[idx] = run; cur[idx] = run; run += vals[i]; }
    }
    if (t == 1023) off[NAT] = part[1023];
}

// scatter payloads: tdata 12B (rij, rik, cos); edata 8B (dist, a1)
__global__ __launch_bounds__(256) void scatter_k(const int* __restrict__ tri,
                                                 const int* __restrict__ nl,
                                                 const float* __restrict__ rij,
                                                 const float* __restrict__ rik,
                                                 const float* __restrict__ ang,
                                                 const float* __restrict__ dist,
                                                 int* __restrict__ tcur, int* __restrict__ ecur,
                                                 float* __restrict__ tdata,
                                                 float2* __restrict__ edata) {
    int stride = gridDim.x * 256;
    for (int g = blockIdx.x * 256 + threadIdx.x; g < NT + NE; g += stride) {
        if (g < NT) {
            int p = atomicAdd(&tcur[tri[(size_t)g * 3 + 1]], 1);
            float* dst = tdata + (size_t)p * 3;
            dst[0] = rij[g];
            dst[1] = rik[g];
            dst[2] = __cosf(ang[g]);
        } else {
            int e = g - NT;
            int p = atomicAdd(&ecur[nl[e]], 1);
            edata[p] = make_float2(dist[e], __int_as_float(nl[NE + e]));
        }
    }
}

// ---------------- K4: fused three-body + two-body ----------------
// R10: one kernel, each wave alternates threebody_atom(a) / twobody_atom(a).
// Waves desync on variable atom sizes -> at any instant the CU mixes
// VALU-heavy threebody waves with gather-latency twobody waves; twobody
// rides threebody's ~36% stall slots instead of serializing after it.
__global__ __launch_bounds__(256) void fused_bodies(const float* __restrict__ tdata,
                                                    const int* __restrict__ toff,
                                                    const float2* __restrict__ edata,
                                                    const int* __restrict__ eoff,
                                                    const float* __restrict__ h,
                                                    const float* __restrict__ lut,
                                                    const float* __restrict__ thW1,
                                                    const float* __restrict__ thW2,
                                                    const float* __restrict__ thG1,
                                                    const float* __restrict__ thG2,
                                                    float* __restrict__ W3,
                                                    float* __restrict__ acc) {
    __shared__ __bf16 lw2[64 * 128];
    __shared__ __bf16 lg2[64 * 128];
    __shared__ float lw1[192];
    __shared__ float lg1[192];
    int tid = threadIdx.x;
    for (int i = tid; i < 192; i += 256) { lw1[i] = thW1[i]; lg1[i] = thG1[i]; }
    // B-fragment swizzle (validated R1/R2): (k,c) -> (((tile*2+s)*64)+q*16+n)*8+j
    for (int e = tid; e < 64 * 128; e += 256) {
        int k = e >> 7, c = e & 127;
        int tile = c >> 4, n = c & 15, s = k >> 5, q = (k >> 3) & 3, j = k & 7;
        int li = ((((tile << 1) + s) * 64) + (q << 4) + n) * 8 + j;
        lw2[li] = (__bf16)thW2[e];
        lg2[li] = (__bf16)thG2[e];
    }
    __syncthreads();

    int lane = tid & 63;
    int q = lane >> 4, n = lane & 15;
    int lfrag = ((q << 4) + n) << 3;
    int c2 = lane << 1;   // twobody channel pair
    int wid = (blockIdx.x << 2) + (tid >> 6);
    int nw = gridDim.x << 2;

    for (int a = wid; a < NAT; a += nw) {
        // ---------- threebody atom ----------
        {
            int base = toff[a];
            int cnt = toff[a + 1] - base;
            floatx2 accT[8];
#pragma unroll
            for (int t = 0; t < 8; ++t) accT[t] = floatx2{0.f, 0.f};

            for (int i0 = 0; i0 < cnt; i0 += 64) {
                int rem = cnt - i0;
                float tx = 0.f, ty = 0.f, tz = 0.f;
                if (lane < rem) {
                    const float* p = tdata + (size_t)(base + i0 + lane) * 3;
                    tx = p[0]; ty = p[1]; tz = p[2];
                }
                float rrv[4], kkv[4], ccv[4];
#pragma unroll
                for (int ms = 0; ms < 4; ++ms) {
                    rrv[ms] = __shfl(tx, (ms << 4) + n);
                    kkv[ms] = __shfl(ty, (ms << 4) + n);
                    ccv[ms] = __shfl(tz, (ms << 4) + n);
                }
                int nms = rem >= 64 ? 4 : ((rem + 15) >> 4);

                // A-fragments: weight reads hoisted out of ms loop (48 vs 192 LDS bcast/chunk)
                bf16x8 fam[4][2], fag[4][2];
#pragma unroll
                for (int s = 0; s < 2; ++s) {
                    int kb = s * 32 + (q << 3);
#pragma unroll
                    for (int j2 = 0; j2 < 4; ++j2) {
                        floatx2 wa0 = *(const floatx2*)&lw1[kb + 2 * j2];
                        floatx2 wa1 = *(const floatx2*)&lw1[64 + kb + 2 * j2];
                        floatx2 wa2 = *(const floatx2*)&lw1[128 + kb + 2 * j2];
                        floatx2 wb0 = *(const floatx2*)&lg1[kb + 2 * j2];
                        floatx2 wb1 = *(const floatx2*)&lg1[64 + kb + 2 * j2];
                        floatx2 wb2 = *(const floatx2*)&lg1[128 + kb + 2 * j2];
#pragma unroll
                        for (int ms = 0; ms < 4; ++ms) {
                            if (ms >= nms) break;   // wave-uniform
                            floatx2 rr2 = {rrv[ms], rrv[ms]};
                            floatx2 kk2 = {kkv[ms], kkv[ms]};
                            floatx2 cc2 = {ccv[ms], ccv[ms]};
                            floatx2 um = rr2 * wa0 + kk2 * wa1 + cc2 * wa2;
                            floatx2 ug = rr2 * wb0 + kk2 * wb1 + cc2 * wb2;
                            floatx2 sm = fsilu2(um);
                            floatx2 sg = fsilu2(ug);
                            fam[ms][s][2 * j2]     = (__bf16)sm.x;
                            fam[ms][s][2 * j2 + 1] = (__bf16)sm.y;
                            fag[ms][s][2 * j2]     = (__bf16)sg.x;
                            fag[ms][s][2 * j2 + 1] = (__bf16)sg.y;
                        }
                    }
                }

                // tile-outer: one B read serves all ms batches (R9)
#pragma unroll
                for (int tile = 0; tile < 8; ++tile) {
                    __builtin_amdgcn_sched_barrier(0);  // cap B prefetch at one tile
                    const __bf16* pw = lw2 + lfrag + tile * 1024;
                    const __bf16* pg = lg2 + lfrag + tile * 1024;
                    bf16x8 bw0 = *(const bf16x8*)(pw);
                    bf16x8 bw1 = *(const bf16x8*)(pw + 512);
                    bf16x8 bg0 = *(const bf16x8*)(pg);
                    bf16x8 bg1 = *(const bf16x8*)(pg + 512);
#pragma unroll
                    for (int ms = 0; ms < 4; ++ms) {
                        if (ms >= nms) break;
                        floatx4 am = {0.f, 0.f, 0.f, 0.f};
                        floatx4 ag = {0.f, 0.f, 0.f, 0.f};
                        am = __builtin_amdgcn_mfma_f32_16x16x32_bf16(fam[ms][0], bw0, am, 0, 0, 0);
                        am = __builtin_amdgcn_mfma_f32_16x16x32_bf16(fam[ms][1], bw1, am, 0, 0, 0);
                        ag = __builtin_amdgcn_mfma_f32_16x16x32_bf16(fag[ms][0], bg0, ag, 0, 0, 0);
                        ag = __builtin_amdgcn_mfma_f32_16x16x32_bf16(fag[ms][1], bg1, ag, 0, 0, 0);
                        floatx2 s01 = fsigmoid2(floatx2{ag[0], ag[1]});
                        floatx2 s23 = fsigmoid2(floatx2{ag[2], ag[3]});
                        accT[tile] += floatx2{am[0], am[1]} * s01
                                    + floatx2{am[2], am[3]} * s23;
                    }
                }
            }
#pragma unroll
            for (int tile = 0; tile < 8; ++tile) {
                float v = accT[tile].x + accT[tile].y;
                v += __shfl_xor(v, 16);
                v += __shfl_xor(v, 32);
                if (q == 0) W3[(size_t)a * 128 + (tile << 4) + n] = v;
            }
        }
        // ---------- twobody atom (latency-bound; rides threebody stalls) ----------
        {
            int base = eoff[a];
            int cnt = eoff[a + 1] - base;
            float s0 = 0.f, s1 = 0.f, t0 = 0.f, t1 = 0.f;
            for (int i0 = 0; i0 < cnt; i0 += 64) {
                int rem = cnt - i0; if (rem > 64) rem = 64;
                float2 el = make_float2(0.f, 0.f);
                if (lane < rem) el = edata[base + i0 + lane];
                int j = 0;
                for (; j + 2 <= rem; j += 2) {
                    float dA = __shfl(el.x, j);
                    int aA = __float_as_int(__shfl(el.y, j));
                    float dB = __shfl(el.x, j + 1);
                    int aB = __float_as_int(__shfl(el.y, j + 1));
                    float xA = dA * ((float)NB / 5.0f);
                    int iA = (int)xA; if (iA > NB - 1) iA = NB - 1;
                    float fA = xA - (float)iA;
                    float xB = dB * ((float)NB / 5.0f);
                    int iB = (int)xB; if (iB > NB - 1) iB = NB - 1;
                    float fB = xB - (float)iB;
                    float2 l0A = *(const float2*)&lut[(size_t)iA * 128 + c2];
                    float2 l1A = *(const float2*)&lut[(size_t)(iA + 1) * 128 + c2];
                    float2 hvA = *(const float2*)&h[(size_t)aA * 128 + c2];
                    float2 l0B = *(const float2*)&lut[(size_t)iB * 128 + c2];
                    float2 l1B = *(const float2*)&lut[(size_t)(iB + 1) * 128 + c2];
                    float2 hvB = *(const float2*)&h[(size_t)aB * 128 + c2];
                    s0 += hvA.x * (l0A.x + (l1A.x - l0A.x) * fA);
                    s1 += hvA.y * (l0A.y + (l1A.y - l0A.y) * fA);
                    t0 += hvB.x * (l0B.x + (l1B.x - l0B.x) * fB);
                    t1 += hvB.y * (l0B.y + (l1B.y - l0B.y) * fB);
                }
                if (j < rem) {
                    float d = __shfl(el.x, j);
                    int a1 = __float_as_int(__shfl(el.y, j));
                    float x = d * ((float)NB / 5.0f);
                    int i = (int)x; if (i > NB - 1) i = NB - 1;
                    float f = x - (float)i;
                    float2 l0 = *(const float2*)&lut[(size_t)i * 128 + c2];
                    float2 l1 = *(const float2*)&lut[(size_t)(i + 1) * 128 + c2];
                    float2 hv = *(const float2*)&h[(size_t)a1 * 128 + c2];
                    s0 += hv.x * (l0.x + (l1.x - l0.x) * f);
                    s1 += hv.y * (l0.y + (l1.y - l0.y) * f);
                }
            }
            acc[(size_t)a * 128 + c2] = s0 + t0;
            acc[(size_t)a * 128 + c2 + 1] = s1 + t1;
        }
    }
}

// ---------------- K5: inject three-body rows (after fused_bodies) ----------------
__global__ __launch_bounds__(256) void inject(const float* __restrict__ h,
                                              const float* __restrict__ W3,
                                              const int* __restrict__ nl,
                                              float* __restrict__ acc) {
    int g = blockIdx.x * 256 + threadIdx.x;
    int row = g >> 7, c = g & 127;
    float v = h[g] * W3[g];
    unsafeAtomicAdd(&acc[(size_t)nl[row] * 128 + c], v);
}

extern "C" void kernel_launch(void* const* d_in, const int* in_sizes, int n_in,
                              void* d_out, int out_size, void* d_ws, size_t ws_size,
                              hipStream_t stream) {
    const float* features = (const float*)d_in[0];
    const float* dist = (const float*)d_in[1];
    const float* ang = (const float*)d_in[2];
    const float* rij = (const float*)d_in[3];
    const float* rik = (const float*)d_in[4];
    const int* nl = (const int*)d_in[5];
    const int* tri = (const int*)d_in[6];
    const float* W_pre = (const float*)d_in[7];
    const float* tbW1 = (const float*)d_in[8];
    const float* tbW2 = (const float*)d_in[9];
    const float* tbG1 = (const float*)d_in[10];
    const float* tbG2 = (const float*)d_in[11];
    const float* thW1 = (const float*)d_in[12];
    const float* thW2 = (const float*)d_in[13];
    const float* thG1 = (const float*)d_in[14];
    const float* thG2 = (const float*)d_in[15];
    const float* W_post = (const float*)d_in[16];
    float* out = (float*)d_out;

    // workspace layout (~52 MB); acc aliases d_out
    float* tdata = (float*)d_ws;                         // NT * 12B = 24 MB
    float2* edata = (float2*)(tdata + (size_t)NT * 3);   // NE * 8B = 5.1 MB
    float* h   = (float*)(edata + NE);                   // 10.24 MB
    float* W3  = h + (size_t)NAT * CH;                   // 10.24 MB
    float* lut = W3 + (size_t)NAT * CH;                  // 2.1 MB
    int* tcnt = (int*)(lut + (size_t)(NB + 1) * CH);
    int* ecnt = tcnt + NAT;
    int* toff = ecnt + NAT;                              // NAT+1
    int* eoff = toff + NAT + 1;                          // NAT+1
    int* tcur = eoff + NAT + 1;
    int* ecur = tcur + NAT;
    float* acc = out;

    hipMemsetAsync(tcnt, 0, (size_t)2 * NAT * sizeof(int), stream);

    gemm128<<<NAT / 32, 256, 0, stream>>>(features, W_pre, h);
    build_lut<<<NB + 1, 128, 0, stream>>>(tbW1, tbW2, tbG1, tbG2, lut);
    hist_k<<<1024, 256, 0, stream>>>(tri, nl, tcnt, ecnt);
    scan20k<<<2, 1024, 0, stream>>>(tcnt, toff, tcur, ecnt, eoff, ecur);
    scatter_k<<<1024, 256, 0, stream>>>(tri, nl, rij, rik, ang, dist,
                                        tcur, ecur, tdata, edata);
    fused_bodies<<<1024, 256, 0, stream>>>(tdata, toff, edata, eoff, h, lut,
                                           thW1, thW2, thG1, thG2, W3, acc);
    inject<<<NAT * CH / 256, 256, 0, stream>>>(h, W3, nl, acc);
    gemm128<<<NAT / 32, 256, 0, stream>>>(acc, W_post, out);
}